// Round 1
// baseline (233.106 us; speedup 1.0000x reference)
//
#include <hip/hip_runtime.h>
#include <hip/hip_bf16.h>
#include <math.h>

#define B_ 4
#define S_ 2048
#define DM_ 512
#define H_ 8
#define DH_ 64
#define DOUT_ 512
#define W_ 8
#define NS_ 2
#define T_ (NS_ + S_)      // 2050 rows per batch in xc
#define M_TOT (B_ * T_)    // 8200
#define N3 1536            // q | k | v concatenated columns

// ---------------------------------------------------------------------------
// Kernel 1: y[row][n] = xc[row] @ [Wq | Wk | Wv][:, n]  (+bk on the k third)
// xc row -> (b = row/2050, t = row%2050); t<NS -> sink, else x.
// Classic 64x64x16 f32 tile, 256 threads, 4x4 per thread.
// ---------------------------------------------------------------------------
__global__ __launch_bounds__(256) void proj_gemm(
    const float* __restrict__ x, const float* __restrict__ sink,
    const float* __restrict__ Wq, const float* __restrict__ Wk,
    const float* __restrict__ Wv, const float* __restrict__ bk,
    float* __restrict__ y)
{
    __shared__ __align__(16) float As[16][64];   // [k][m]
    __shared__ __align__(16) float Bs[16][64];   // [k][n]
    const int tid  = threadIdx.x;
    const int bn   = blockIdx.x;                 // 0..23  (col tile)
    const int bm   = blockIdx.y;                 // 0..128 (row tile)
    const int row0 = bm * 64;
    const int col0 = bn * 64;

    // whole 64-col tile lives inside one weight matrix (512 % 64 == 0)
    const float* Wsrc; int nbase; bool isk;
    if (col0 < 512)       { Wsrc = Wq; nbase = col0;        isk = false; }
    else if (col0 < 1024) { Wsrc = Wk; nbase = col0 - 512;  isk = true;  }
    else                  { Wsrc = Wv; nbase = col0 - 1024; isk = false; }

    const int tx = tid & 15, ty = tid >> 4;      // 16x16 thread grid
    float acc[4][4] = {};

    // loader mapping (shared by A and B stagers)
    const int lrow = tid & 63, lk4 = tid >> 6;   // lk4 in 0..3
    const float* arow = nullptr;
    {
        int row = row0 + lrow;
        if (row < M_TOT) {
            int b = row / T_;
            int t = row - b * T_;
            arow = (t < NS_) ? (sink + ((size_t)b * NS_ + t) * DM_)
                             : (x    + ((size_t)b * S_  + (t - NS_)) * DM_);
        }
    }

    for (int k0 = 0; k0 < DM_; k0 += 16) {
        // stage A: 64 rows x 16 k, float4 per thread
        float4 a4 = make_float4(0.f, 0.f, 0.f, 0.f);
        if (arow) a4 = *(const float4*)(arow + k0 + lk4 * 4);
        As[lk4 * 4 + 0][lrow] = a4.x;
        As[lk4 * 4 + 1][lrow] = a4.y;
        As[lk4 * 4 + 2][lrow] = a4.z;
        As[lk4 * 4 + 3][lrow] = a4.w;
        // stage B: 16 k x 64 n, 4 scalar (coalesced over n) per thread
        #pragma unroll
        for (int kk = 0; kk < 16; kk += 4)
            Bs[kk + lk4][lrow] =
                Wsrc[(size_t)(k0 + kk + lk4) * DOUT_ + nbase + lrow];
        __syncthreads();

        #pragma unroll
        for (int kk = 0; kk < 16; ++kk) {
            float4 a = *(const float4*)&As[kk][ty * 4];
            float4 b = *(const float4*)&Bs[kk][tx * 4];
            float av[4] = {a.x, a.y, a.z, a.w};
            float bv[4] = {b.x, b.y, b.z, b.w};
            #pragma unroll
            for (int i = 0; i < 4; ++i)
                #pragma unroll
                for (int j = 0; j < 4; ++j)
                    acc[i][j] = fmaf(av[i], bv[j], acc[i][j]);
        }
        __syncthreads();
    }

    // epilogue: float4 stores, bias folded in for the k third
    float4 bias = make_float4(0.f, 0.f, 0.f, 0.f);
    if (isk) bias = *(const float4*)&bk[nbase + tx * 4];
    #pragma unroll
    for (int i = 0; i < 4; ++i) {
        int row = row0 + ty * 4 + i;
        if (row >= M_TOT) continue;
        float4 o = make_float4(acc[i][0] + bias.x, acc[i][1] + bias.y,
                               acc[i][2] + bias.z, acc[i][3] + bias.w);
        *(float4*)&y[(size_t)row * N3 + col0 + tx * 4] = o;
    }
}

// ---------------------------------------------------------------------------
// Kernel 2: per (b,s,c) 10-way relative attention.
//   p < NS (sinks):   sc = (q[b,p,c]      + pos[dh][p]) * k[b,s,c]
//   p = NS+r, r<W:    sc = (q[b,NS+s+r,c] + pos[dh][p]) * k[b,s,c]  if s+r<S
//   softmax over p, then weighted sum of the matching v values.
// q/k/v are the thirds of y; out[b][s][c] is coalesced over c.
// ---------------------------------------------------------------------------
__global__ __launch_bounds__(512) void attn_kernel(
    const float* __restrict__ y, const float* __restrict__ pos,
    float* __restrict__ out)
{
    __shared__ float spos[DH_ * (NS_ + W_)];
    for (int i = threadIdx.x; i < DH_ * (NS_ + W_); i += 512) spos[i] = pos[i];
    __syncthreads();

    const int c  = threadIdx.x;                 // channel 0..511
    const int bs = blockIdx.x;
    const int s  = bs & (S_ - 1);
    const int b  = bs >> 11;                    // S_ == 2048
    const float* yb = y + (size_t)b * T_ * N3;
    const float kv  = yb[(size_t)(NS_ + s) * N3 + 512 + c];
    const int dh    = c & (DH_ - 1);

    float sc[NS_ + W_], vv[NS_ + W_];
    #pragma unroll
    for (int p = 0; p < NS_; ++p) {
        float qv = yb[(size_t)p * N3 + c] + spos[dh * (NS_ + W_) + p];
        sc[p] = qv * kv;
        vv[p] = yb[(size_t)p * N3 + 1024 + c];
    }
    const int nv = (S_ - s < W_) ? (S_ - s) : W_;
    #pragma unroll
    for (int r = 0; r < W_; ++r) {
        if (r < nv) {
            size_t t = (size_t)(NS_ + s + r) * N3;
            float qv = yb[t + c] + spos[dh * (NS_ + W_) + NS_ + r];
            sc[NS_ + r] = qv * kv;
            vv[NS_ + r] = yb[t + 1024 + c];
        } else {
            sc[NS_ + r] = -INFINITY;
            vv[NS_ + r] = 0.f;
        }
    }

    float m = sc[0];
    #pragma unroll
    for (int p = 1; p < NS_ + W_; ++p) m = fmaxf(m, sc[p]);
    float sum = 0.f, accv = 0.f;
    #pragma unroll
    for (int p = 0; p < NS_ + W_; ++p) {
        float e = __expf(sc[p] - m);
        sum += e;
        accv = fmaf(e, vv[p], accv);
    }
    out[((size_t)b * S_ + s) * DOUT_ + c] = accv / sum;
}

// ---------------------------------------------------------------------------
extern "C" void kernel_launch(void* const* d_in, const int* in_sizes, int n_in,
                              void* d_out, int out_size, void* d_ws, size_t ws_size,
                              hipStream_t stream) {
    const float* x    = (const float*)d_in[0];
    const float* sink = (const float*)d_in[1];
    const float* Wk   = (const float*)d_in[2];
    const float* bk   = (const float*)d_in[3];
    const float* Wq   = (const float*)d_in[4];
    const float* Wv   = (const float*)d_in[5];
    const float* pos  = (const float*)d_in[6];

    float* y = (float*)d_ws;                    // 8200 x 1536 f32 = 50.4 MB

    dim3 g1(N3 / 64, (M_TOT + 63) / 64);        // 24 x 129
    proj_gemm<<<g1, 256, 0, stream>>>(x, sink, Wq, Wk, Wv, bk, y);

    attn_kernel<<<dim3(B_ * S_), 512, 0, stream>>>(y, pos, (float*)d_out);
}

// Round 4
// 95.250 us; speedup vs baseline: 2.4473x; 2.4473x over previous
//
#include <hip/hip_runtime.h>
#include <hip/hip_bf16.h>
#include <math.h>
#include <stdint.h>

#define B_ 4
#define S_ 2048
#define DM_ 512
#define H_ 8
#define DH_ 64
#define DOUT_ 512
#define W_ 8
#define NS_ 2
#define T_ (NS_ + S_)      // 2050 rows per batch in xc
#define M_TOT (B_ * T_)    // 8200
#define M_PAD 8320         // 65 * 128, zero-padded tail
#define N3 1536            // q | k | v concatenated columns

typedef __attribute__((ext_vector_type(8))) __bf16   bf16x8;
typedef __attribute__((ext_vector_type(4))) float    f32x4;
typedef __attribute__((ext_vector_type(8))) uint16_t u16x8;

__device__ inline uint16_t f2bf(float f) {          // RNE f32 -> bf16
    uint32_t u = __builtin_bit_cast(uint32_t, f);
    u += 0x7FFF + ((u >> 16) & 1);
    return (uint16_t)(u >> 16);
}

// ---------------------------------------------------------------------------
// convA: xc (sink|x rows) -> bf16 [M_PAD][512], zero pad rows >= M_TOT.
// ---------------------------------------------------------------------------
__global__ __launch_bounds__(256) void convA(
    const float* __restrict__ x, const float* __restrict__ sink,
    uint16_t* __restrict__ Abf)
{
    size_t id = (size_t)blockIdx.x * 256 + threadIdx.x;   // one 8-elem chunk
    size_t e0 = id * 8;
    int row = (int)(e0 >> 9);
    int col = (int)(e0 & 511);
    u16x8 o;
    if (row < M_TOT) {
        int b = row / T_;
        int t = row - b * T_;
        const float* src = (t < NS_)
            ? &sink[((size_t)b * NS_ + t) * DM_ + col]
            : &x[((size_t)b * S_ + (t - NS_)) * DM_ + col];
        float4 v0 = *(const float4*)src;
        float4 v1 = *(const float4*)(src + 4);
        o[0] = f2bf(v0.x); o[1] = f2bf(v0.y); o[2] = f2bf(v0.z); o[3] = f2bf(v0.w);
        o[4] = f2bf(v1.x); o[5] = f2bf(v1.y); o[6] = f2bf(v1.z); o[7] = f2bf(v1.w);
    } else {
        o = (u16x8)0;
    }
    *(u16x8*)&Abf[e0] = o;
}

// ---------------------------------------------------------------------------
// convB: Bt[n][k] = W(n)[k][n%512] in bf16  (transpose + convert via LDS tile)
// grid (N3/64, DM_/32), 256 threads.
// ---------------------------------------------------------------------------
__global__ __launch_bounds__(256) void convB(
    const float* __restrict__ Wq, const float* __restrict__ Wk,
    const float* __restrict__ Wv, uint16_t* __restrict__ Bt)
{
    __shared__ float tile[32][65];
    const int n0 = blockIdx.x * 64, k0 = blockIdx.y * 32;
    const float* Wsrc = (n0 < 512) ? Wq : ((n0 < 1024) ? Wk : Wv);
    const int nb = n0 & 511;
    const int tid = threadIdx.x;
    const int nn = tid & 63, kk = tid >> 6;          // kk 0..3
    #pragma unroll
    for (int i = 0; i < 8; ++i)
        tile[kk + i * 4][nn] = Wsrc[(size_t)(k0 + kk + i * 4) * DOUT_ + nb + nn];
    __syncthreads();
    const int nn2 = tid >> 2, k8 = (tid & 3) * 8;
    u16x8 o;
    #pragma unroll
    for (int j = 0; j < 8; ++j) o[j] = f2bf(tile[k8 + j][nn2]);
    *(u16x8*)&Bt[(size_t)(n0 + nn2) * DM_ + k0 + k8] = o;
}

// ---------------------------------------------------------------------------
// gemm_bf16: y[M][N3] = Abf[M][512] * Bt[N3][512]^T (+bk on cols 512..1023)
// 128x128 tile, BK=32, 4 waves (2x2), 16x16x32 MFMA, global_load_lds w=16.
// Swizzle: linear LDS dest, inverse-swizzled global source, swizzled reads.
// ---------------------------------------------------------------------------
__global__ __launch_bounds__(256) void gemm_bf16(
    const uint16_t* __restrict__ Abf, const uint16_t* __restrict__ Bt,
    const float* __restrict__ bk, float* __restrict__ y)
{
    __shared__ __align__(16) uint16_t As[128 * 32];
    __shared__ __align__(16) uint16_t Bs[128 * 32];
    const int tid  = threadIdx.x;
    const int wave = tid >> 6, lane = tid & 63;
    const int row0 = blockIdx.y * 128, col0 = blockIdx.x * 128;
    const int wm = wave >> 1, wn = wave & 1;         // 2x2 wave grid
    f32x4 acc[4][4] = {};

    const int srow  = tid >> 2;                      // staging row 0..63
    const int sslot = tid & 3;                       // 16B slot in row

    for (int k0 = 0; k0 < DM_; k0 += 32) {
        #pragma unroll
        for (int i = 0; i < 2; ++i) {
            const int r  = i * 64 + srow;
            const int ls = sslot ^ ((r >> 1) & 3);   // inverse swizzle on src
            const uint16_t* ga = Abf + (size_t)(row0 + r) * DM_ + k0 + ls * 8;
            const uint16_t* gb = Bt  + (size_t)(col0 + r) * DM_ + k0 + ls * 8;
            __builtin_amdgcn_global_load_lds(
                (const __attribute__((address_space(1))) void*)ga,
                (__attribute__((address_space(3))) void*)(As + i * 2048 + wave * 512),
                16, 0, 0);
            __builtin_amdgcn_global_load_lds(
                (const __attribute__((address_space(1))) void*)gb,
                (__attribute__((address_space(3))) void*)(Bs + i * 2048 + wave * 512),
                16, 0, 0);
        }
        __syncthreads();

        const int kslot = lane >> 4;                 // which 8-wide k slice
        const int fr    = lane & 15;
        bf16x8 af[4], bfr[4];
        #pragma unroll
        for (int mi = 0; mi < 4; ++mi) {
            const int r  = wm * 64 + mi * 16 + fr;
            const int ss = kslot ^ ((r >> 1) & 3);
            af[mi] = *(const bf16x8*)&As[r * 32 + ss * 8];
        }
        #pragma unroll
        for (int ni = 0; ni < 4; ++ni) {
            const int r  = wn * 64 + ni * 16 + fr;
            const int ss = kslot ^ ((r >> 1) & 3);
            bfr[ni] = *(const bf16x8*)&Bs[r * 32 + ss * 8];
        }
        #pragma unroll
        for (int mi = 0; mi < 4; ++mi)
            #pragma unroll
            for (int ni = 0; ni < 4; ++ni)
                acc[mi][ni] = __builtin_amdgcn_mfma_f32_16x16x32_bf16(
                    af[mi], bfr[ni], acc[mi][ni], 0, 0, 0);
        __syncthreads();
    }

    // epilogue: C row = (lane>>4)*4 + reg (m side), col = lane&15 (n side)
    const int fr = lane & 15, fq = lane >> 4;
    #pragma unroll
    for (int ni = 0; ni < 4; ++ni) {
        const int col = col0 + wn * 64 + ni * 16 + fr;
        const float bias = (col >= 512 && col < 1024) ? bk[col - 512] : 0.f;
        #pragma unroll
        for (int mi = 0; mi < 4; ++mi) {
            #pragma unroll
            for (int r4 = 0; r4 < 4; ++r4) {
                const int row = row0 + wm * 64 + mi * 16 + fq * 4 + r4;
                if (row < M_TOT)
                    y[(size_t)row * N3 + col] = acc[mi][ni][r4] + bias;
            }
        }
    }
}

// ---------------------------------------------------------------------------
// attn: per (b,s,c) 10-way relative attention over y (f32). Unchanged.
// ---------------------------------------------------------------------------
__global__ __launch_bounds__(512) void attn_kernel(
    const float* __restrict__ y, const float* __restrict__ pos,
    float* __restrict__ out)
{
    __shared__ float spos[DH_ * (NS_ + W_)];
    for (int i = threadIdx.x; i < DH_ * (NS_ + W_); i += 512) spos[i] = pos[i];
    __syncthreads();

    const int c  = threadIdx.x;
    const int bs = blockIdx.x;
    const int s  = bs & (S_ - 1);
    const int b  = bs >> 11;
    const float* yb = y + (size_t)b * T_ * N3;
    const float kv  = yb[(size_t)(NS_ + s) * N3 + 512 + c];
    const int dh    = c & (DH_ - 1);

    float sc[NS_ + W_], vv[NS_ + W_];
    #pragma unroll
    for (int p = 0; p < NS_; ++p) {
        float qv = yb[(size_t)p * N3 + c] + spos[dh * (NS_ + W_) + p];
        sc[p] = qv * kv;
        vv[p] = yb[(size_t)p * N3 + 1024 + c];
    }
    const int nv = (S_ - s < W_) ? (S_ - s) : W_;
    #pragma unroll
    for (int r = 0; r < W_; ++r) {
        if (r < nv) {
            size_t t = (size_t)(NS_ + s + r) * N3;
            float qv = yb[t + c] + spos[dh * (NS_ + W_) + NS_ + r];
            sc[NS_ + r] = qv * kv;
            vv[NS_ + r] = yb[t + 1024 + c];
        } else {
            sc[NS_ + r] = -INFINITY;
            vv[NS_ + r] = 0.f;
        }
    }

    float m = sc[0];
    #pragma unroll
    for (int p = 1; p < NS_ + W_; ++p) m = fmaxf(m, sc[p]);
    float sum = 0.f, accv = 0.f;
    #pragma unroll
    for (int p = 0; p < NS_ + W_; ++p) {
        float e = __expf(sc[p] - m);
        sum += e;
        accv = fmaf(e, vv[p], accv);
    }
    out[((size_t)b * S_ + s) * DOUT_ + c] = accv / sum;
}

// ---------------------------------------------------------------------------
extern "C" void kernel_launch(void* const* d_in, const int* in_sizes, int n_in,
                              void* d_out, int out_size, void* d_ws, size_t ws_size,
                              hipStream_t stream) {
    const float* x    = (const float*)d_in[0];
    const float* sink = (const float*)d_in[1];
    const float* Wk   = (const float*)d_in[2];
    const float* bk   = (const float*)d_in[3];
    const float* Wq   = (const float*)d_in[4];
    const float* Wv   = (const float*)d_in[5];
    const float* pos  = (const float*)d_in[6];

    char* ws = (char*)d_ws;
    float*    y   = (float*)ws;                                   // 50,380,800 B
    uint16_t* Abf = (uint16_t*)(ws + (size_t)M_TOT * N3 * 4);     //  8,519,680 B
    uint16_t* Bt  = (uint16_t*)(ws + (size_t)M_TOT * N3 * 4
                                   + (size_t)M_PAD * DM_ * 2);    //  1,572,864 B

    convA<<<dim3(M_PAD * DM_ / 8 / 256), 256, 0, stream>>>(x, sink, Abf);
    convB<<<dim3(N3 / 64, DM_ / 32), 256, 0, stream>>>(Wq, Wk, Wv, Bt);
    gemm_bf16<<<dim3(N3 / 128, M_PAD / 128), 256, 0, stream>>>(Abf, Bt, bk, y);
    attn_kernel<<<dim3(B_ * S_), 512, 0, stream>>>(y, pos, (float*)d_out);
}

// Round 5
// 70.462 us; speedup vs baseline: 3.3083x; 1.3518x over previous
//
#include <hip/hip_runtime.h>
#include <hip/hip_bf16.h>
#include <math.h>
#include <stdint.h>

#define B_ 4
#define S_ 2048
#define DM_ 512
#define H_ 8
#define DH_ 64
#define DOUT_ 512
#define W_ 8
#define NS_ 2
#define T_ (NS_ + S_)      // 2050 rows per batch in xc
#define M_TOT (B_ * T_)    // 8200
#define M_PAD 8320         // 65 * 128, zero-padded tail
#define N3 1536            // q | k | v concatenated columns
#define SCHUNK 32          // s-strip per thread in attn

typedef __attribute__((ext_vector_type(8))) __bf16   bf16x8;
typedef __attribute__((ext_vector_type(4))) float    f32x4;
typedef __attribute__((ext_vector_type(8))) uint16_t u16x8;

__device__ inline uint16_t f2bf(float f) {          // RNE f32 -> bf16
    uint32_t u = __builtin_bit_cast(uint32_t, f);
    u += 0x7FFF + ((u >> 16) & 1);
    return (uint16_t)(u >> 16);
}

// ---------------------------------------------------------------------------
// convA: xc (sink|x rows) -> bf16 [M_PAD][512], zero pad rows >= M_TOT.
// ---------------------------------------------------------------------------
__global__ __launch_bounds__(256) void convA(
    const float* __restrict__ x, const float* __restrict__ sink,
    uint16_t* __restrict__ Abf)
{
    size_t id = (size_t)blockIdx.x * 256 + threadIdx.x;   // one 8-elem chunk
    size_t e0 = id * 8;
    int row = (int)(e0 >> 9);
    int col = (int)(e0 & 511);
    u16x8 o;
    if (row < M_TOT) {
        int b = row / T_;
        int t = row - b * T_;
        const float* src = (t < NS_)
            ? &sink[((size_t)b * NS_ + t) * DM_ + col]
            : &x[((size_t)b * S_ + (t - NS_)) * DM_ + col];
        float4 v0 = *(const float4*)src;
        float4 v1 = *(const float4*)(src + 4);
        o[0] = f2bf(v0.x); o[1] = f2bf(v0.y); o[2] = f2bf(v0.z); o[3] = f2bf(v0.w);
        o[4] = f2bf(v1.x); o[5] = f2bf(v1.y); o[6] = f2bf(v1.z); o[7] = f2bf(v1.w);
    } else {
        o = (u16x8)0;
    }
    *(u16x8*)&Abf[e0] = o;
}

// ---------------------------------------------------------------------------
// convB: Bt[n][k] = W(n)[k][n%512] in bf16  (transpose + convert via LDS tile)
// ---------------------------------------------------------------------------
__global__ __launch_bounds__(256) void convB(
    const float* __restrict__ Wq, const float* __restrict__ Wk,
    const float* __restrict__ Wv, uint16_t* __restrict__ Bt)
{
    __shared__ float tile[32][65];
    const int n0 = blockIdx.x * 64, k0 = blockIdx.y * 32;
    const float* Wsrc = (n0 < 512) ? Wq : ((n0 < 1024) ? Wk : Wv);
    const int nb = n0 & 511;
    const int tid = threadIdx.x;
    const int nn = tid & 63, kk = tid >> 6;          // kk 0..3
    #pragma unroll
    for (int i = 0; i < 8; ++i)
        tile[kk + i * 4][nn] = Wsrc[(size_t)(k0 + kk + i * 4) * DOUT_ + nb + nn];
    __syncthreads();
    const int nn2 = tid >> 2, k8 = (tid & 3) * 8;
    u16x8 o;
    #pragma unroll
    for (int j = 0; j < 8; ++j) o[j] = f2bf(tile[k8 + j][nn2]);
    *(u16x8*)&Bt[(size_t)(n0 + nn2) * DM_ + k0 + k8] = o;
}

// ---------------------------------------------------------------------------
// gemm_bf16: y[M][N3] = Abf[M][512] * Bt[N3][512]^T (+bk on cols 512..1023)
// 128x128 tile, BK=32, 4 waves (2x2), 16x16x32 MFMA, global_load_lds w=16.
// ---------------------------------------------------------------------------
__global__ __launch_bounds__(256) void gemm_bf16(
    const uint16_t* __restrict__ Abf, const uint16_t* __restrict__ Bt,
    const float* __restrict__ bk, float* __restrict__ y)
{
    __shared__ __align__(16) uint16_t As[128 * 32];
    __shared__ __align__(16) uint16_t Bs[128 * 32];
    const int tid  = threadIdx.x;
    const int wave = tid >> 6, lane = tid & 63;
    const int row0 = blockIdx.y * 128, col0 = blockIdx.x * 128;
    const int wm = wave >> 1, wn = wave & 1;         // 2x2 wave grid
    f32x4 acc[4][4] = {};

    const int srow  = tid >> 2;                      // staging row 0..63
    const int sslot = tid & 3;                       // 16B slot in row

    for (int k0 = 0; k0 < DM_; k0 += 32) {
        #pragma unroll
        for (int i = 0; i < 2; ++i) {
            const int r  = i * 64 + srow;
            const int ls = sslot ^ ((r >> 1) & 3);   // inverse swizzle on src
            const uint16_t* ga = Abf + (size_t)(row0 + r) * DM_ + k0 + ls * 8;
            const uint16_t* gb = Bt  + (size_t)(col0 + r) * DM_ + k0 + ls * 8;
            __builtin_amdgcn_global_load_lds(
                (const __attribute__((address_space(1))) void*)ga,
                (__attribute__((address_space(3))) void*)(As + i * 2048 + wave * 512),
                16, 0, 0);
            __builtin_amdgcn_global_load_lds(
                (const __attribute__((address_space(1))) void*)gb,
                (__attribute__((address_space(3))) void*)(Bs + i * 2048 + wave * 512),
                16, 0, 0);
        }
        __syncthreads();

        const int kslot = lane >> 4;                 // which 8-wide k slice
        const int fr    = lane & 15;
        bf16x8 af[4], bfr[4];
        #pragma unroll
        for (int mi = 0; mi < 4; ++mi) {
            const int r  = wm * 64 + mi * 16 + fr;
            const int ss = kslot ^ ((r >> 1) & 3);
            af[mi] = *(const bf16x8*)&As[r * 32 + ss * 8];
        }
        #pragma unroll
        for (int ni = 0; ni < 4; ++ni) {
            const int r  = wn * 64 + ni * 16 + fr;
            const int ss = kslot ^ ((r >> 1) & 3);
            bfr[ni] = *(const bf16x8*)&Bs[r * 32 + ss * 8];
        }
        #pragma unroll
        for (int mi = 0; mi < 4; ++mi)
            #pragma unroll
            for (int ni = 0; ni < 4; ++ni)
                acc[mi][ni] = __builtin_amdgcn_mfma_f32_16x16x32_bf16(
                    af[mi], bfr[ni], acc[mi][ni], 0, 0, 0);
        __syncthreads();
    }

    const int fr = lane & 15, fq = lane >> 4;
    #pragma unroll
    for (int ni = 0; ni < 4; ++ni) {
        const int col = col0 + wn * 64 + ni * 16 + fr;
        const float bias = (col >= 512 && col < 1024) ? bk[col - 512] : 0.f;
        #pragma unroll
        for (int mi = 0; mi < 4; ++mi) {
            #pragma unroll
            for (int r4 = 0; r4 < 4; ++r4) {
                const int row = row0 + wm * 64 + mi * 16 + fq * 4 + r4;
                if (row < M_TOT)
                    y[(size_t)row * N3 + col] = acc[mi][ni][r4] + bias;
            }
        }
    }
}

// ---------------------------------------------------------------------------
// attn: sliding-window. Thread = (b, c), strip of SCHUNK s-values.
// Ring of 8 q/v in registers: 3 new loads per s instead of 21.
// ---------------------------------------------------------------------------
__global__ __launch_bounds__(512) void attn_kernel(
    const float* __restrict__ y, const float* __restrict__ pos,
    float* __restrict__ out)
{
    __shared__ float spos[DH_ * (NS_ + W_)];
    for (int i = threadIdx.x; i < DH_ * (NS_ + W_); i += 512) spos[i] = pos[i];
    __syncthreads();

    const int c  = threadIdx.x;                 // channel 0..511
    const int b  = blockIdx.y;
    const int s0 = blockIdx.x * SCHUNK;
    const float* yb = y + (size_t)b * T_ * N3;
    const int dh = c & (DH_ - 1);

    // per-thread pos registers
    float pp[NS_ + W_];
    #pragma unroll
    for (int p = 0; p < NS_ + W_; ++p) pp[p] = spos[dh * (NS_ + W_) + p];

    // sink q/v (constant over the strip)
    float sq0 = yb[0 * N3 + c],        sq1 = yb[1 * N3 + c];
    float sv0 = yb[0 * N3 + 1024 + c], sv1 = yb[1 * N3 + 1024 + c];

    // prefill ring: q/v rows NS+s0 .. NS+s0+6
    float qr[W_], vr[W_];
    #pragma unroll
    for (int j = 0; j < W_ - 1; ++j) {
        const float* rq = yb + (size_t)(NS_ + s0 + j) * N3 + c;
        qr[j] = rq[0];
        vr[j] = rq[1024];
    }

    for (int i = 0; i < SCHUNK; ++i) {
        const int s = s0 + i;
        int tq = NS_ + s + (W_ - 1);
        if (tq > T_ - 1) tq = T_ - 1;            // clamp (masked below)
        const float* rq = yb + (size_t)tq * N3 + c;
        qr[W_ - 1] = rq[0];
        vr[W_ - 1] = rq[1024];
        const float kv = yb[(size_t)(NS_ + s) * N3 + 512 + c];

        float sc[NS_ + W_];
        sc[0] = (sq0 + pp[0]) * kv;
        sc[1] = (sq1 + pp[1]) * kv;
        #pragma unroll
        for (int r = 0; r < W_; ++r) sc[NS_ + r] = (qr[r] + pp[NS_ + r]) * kv;
        if (s > S_ - W_) {                       // tail masking (block-uniform)
            const int nv = S_ - s;
            #pragma unroll
            for (int r = 0; r < W_; ++r)
                if (r >= nv) sc[NS_ + r] = -INFINITY;
        }

        float m = sc[0];
        #pragma unroll
        for (int p = 1; p < NS_ + W_; ++p) m = fmaxf(m, sc[p]);
        float e[NS_ + W_], sum = 0.f;
        #pragma unroll
        for (int p = 0; p < NS_ + W_; ++p) { e[p] = __expf(sc[p] - m); sum += e[p]; }
        float accv = e[0] * sv0 + e[1] * sv1;
        #pragma unroll
        for (int r = 0; r < W_; ++r) accv = fmaf(e[NS_ + r], vr[r], accv);

        out[((size_t)b * S_ + s) * DOUT_ + c] = accv / sum;

        #pragma unroll
        for (int j = 0; j < W_ - 1; ++j) { qr[j] = qr[j + 1]; vr[j] = vr[j + 1]; }
    }
}

// ---------------------------------------------------------------------------
extern "C" void kernel_launch(void* const* d_in, const int* in_sizes, int n_in,
                              void* d_out, int out_size, void* d_ws, size_t ws_size,
                              hipStream_t stream) {
    const float* x    = (const float*)d_in[0];
    const float* sink = (const float*)d_in[1];
    const float* Wk   = (const float*)d_in[2];
    const float* bk   = (const float*)d_in[3];
    const float* Wq   = (const float*)d_in[4];
    const float* Wv   = (const float*)d_in[5];
    const float* pos  = (const float*)d_in[6];

    char* ws = (char*)d_ws;
    float*    y   = (float*)ws;                                   // 50,380,800 B
    uint16_t* Abf = (uint16_t*)(ws + (size_t)M_TOT * N3 * 4);     //  8,519,680 B
    uint16_t* Bt  = (uint16_t*)(ws + (size_t)M_TOT * N3 * 4
                                   + (size_t)M_PAD * DM_ * 2);    //  1,572,864 B

    convA<<<dim3(M_PAD * DM_ / 8 / 256), 256, 0, stream>>>(x, sink, Abf);
    convB<<<dim3(N3 / 64, DM_ / 32), 256, 0, stream>>>(Wq, Wk, Wv, Bt);
    gemm_bf16<<<dim3(N3 / 128, M_PAD / 128), 256, 0, stream>>>(Abf, Bt, bk, y);
    attn_kernel<<<dim3(S_ / SCHUNK, B_), 512, 0, stream>>>(y, pos, (float*)d_out);
}